// Round 4
// baseline (167.160 us; speedup 1.0000x reference)
//
#include <hip/hip_runtime.h>
#include <hip/hip_bf16.h>

// Problem constants
#define B_    4
#define T_    4096
#define C_    512
#define H_    8
#define D_    64
#define KS_   9
#define PAD_  4
#define MTOT  (B_ * T_)          // 16384
#define PLANE (MTOT * C_)        // elements per q/k/v plane
#define WU    (C_ * C_ / 8)      // weight units of 8 elements

typedef __bf16 bf16_t;
typedef __bf16 bf16x8 __attribute__((ext_vector_type(8)));
typedef float  f32x4  __attribute__((ext_vector_type(4)));

// ---------------------------------------------------------------------------
// fp32 -> bf16 for the 4 weight matrices AND x (GEMM A consumed via
// global_load_lds which cannot convert). 4*WU + PLANE/8 units, 8 elem each.
// ---------------------------------------------------------------------------
__global__ __launch_bounds__(256)
void conv_all(const float* __restrict__ Wq, const float* __restrict__ Wk,
              const float* __restrict__ Wv, const float* __restrict__ Wo,
              const float* __restrict__ x,
              bf16_t* __restrict__ Wb, bf16_t* __restrict__ xb) {
  int i = blockIdx.x * 256 + threadIdx.x;
  const float* src;
  bf16_t* dst;
  if (i < 4 * WU) {                        // WU = 1<<15
    int w = i >> 15;
    const float* W = (w == 0) ? Wq : (w == 1) ? Wk : (w == 2) ? Wv : Wo;
    src = W + (size_t)(i & (WU - 1)) * 8;
    dst = Wb + (size_t)i * 8;
  } else {
    size_t j = (size_t)(i - 4 * WU);
    src = x + j * 8;
    dst = xb + j * 8;
  }
  float4 f0 = ((const float4*)src)[0];
  float4 f1 = ((const float4*)src)[1];
  bf16x8 o;
  o[0] = (bf16_t)f0.x; o[1] = (bf16_t)f0.y; o[2] = (bf16_t)f0.z; o[3] = (bf16_t)f0.w;
  o[4] = (bf16_t)f1.x; o[5] = (bf16_t)f1.y; o[6] = (bf16_t)f1.z; o[7] = (bf16_t)f1.w;
  *(bf16x8*)dst = o;
}

// ---------------------------------------------------------------------------
// Phase-split GEMM, ring-3 LDS, counted vmcnt (T1+T2+T3/T4+T5).
//   C[m][n] = sum_k A[m][k] * Bw[n][k]   (+bias in epilogue)
// BM=256 x BN=128, BK=64, 8 waves as 4m x 2n -> per-wave 64x64 output.
// r4 change vs r3: 2 phases per K-tile (16 MFMA each) instead of 4 (8 each).
//   r3's +1.5us showed tile shape wasn't binding; arithmetic says neither
//   LDS (512cyc/CU/tile) nor MFMA (307cyc) explains ~40us -> phase-latency
//   bound. Halve barrier count (8->4 per K-tile), double MFMA per phase to
//   m201's granularity (16), same staging/swizzle/vmcnt as r3 (verified).
//   P0: read af[0..3]+bfr[0,1] (12 b128); GLD A x4 (kt+2); MFMA m0123 x n01
//   P1: read bfr[2,3] (4);               GLD B x2 (kt+2); MFMA m0123 x n23;
//       boundary vmcnt(6) (kt+2's 6 loads stay in flight; 0 only at last).
// XOR chunk swizzle: LDS slot ch of row r holds global k-chunk ch^(r&7)
// (inverse-swizzled global source, linear gload_lds dest, swizzled ds_read).
// MODE 0: A = xb bf16 [MTOT][C], Bw = Wq|Wk|Wv packed, out -> qkv planes.
// MODE 1: A = y bf16 per-head planes (K-tile kt == head kt), out fp32.
// ---------------------------------------------------------------------------
#define BM   256
#define BN   128
#define BK   64
#define NKT  (C_ / BK)            // 8
#define ASL  (BM * BK)            // 16384 elems per A slot
#define BSL  (BN * BK)            // 8192
#define SLOT (ASL + BSL)          // 24576 elems = 48KB

#define GLD(srcp, off) __builtin_amdgcn_global_load_lds(                     \
    (const __attribute__((address_space(1))) unsigned int*)(srcp),           \
    (__attribute__((address_space(3))) unsigned int*)(&sm[off]), 16, 0, 0)

template<int MODE>
__global__ __launch_bounds__(512, 2)
void gemm8p(const bf16_t* __restrict__ A, const bf16_t* __restrict__ Bw,
            const float* __restrict__ b0, const float* __restrict__ b1,
            const float* __restrict__ b2, void* __restrict__ Outp) {
  __shared__ __align__(16) bf16_t sm[3 * SLOT];

  constexpr int GX  = (MODE == 0) ? (3 * C_ / BN) : (C_ / BN);  // 12 / 4
  constexpr int NWG = GX * (MTOT / BM);                         // 768 / 256
  constexpr int CPX = NWG / 8;                                  // NWG%8==0

  // XCD swizzle (m157): consecutive logical n-blocks (sharing an A panel)
  // land on one XCD's L2.
  const int ord = blockIdx.y * GX + blockIdx.x;
  const int lg  = (ord & 7) * CPX + (ord >> 3);
  const int n0  = (lg % GX) * BN;
  const int m0  = (lg / GX) * BM;

  const int tid  = threadIdx.x;
  const int lane = tid & 63;
  const int wave = tid >> 6;
  const int wm   = wave >> 1;          // 0..3  (64-row slice)
  const int wn   = wave & 1;           // 0..1  (64-col slice)

  // Per-thread staging sources (inverse-swizzled global addresses).
  // A: 2048 16B units (4/thread); B: 1024 units (2/thread).
  const bf16_t* aSrc[4];
  const bf16_t* bSrc[2];
#pragma unroll
  for (int s = 0; s < 4; ++s) {
    int u = s * 512 + tid, r = u >> 3, ch = u & 7;
    int cs = (ch ^ (r & 7)) << 3;
    if constexpr (MODE == 0) {
      aSrc[s] = A + (size_t)(m0 + r) * C_ + cs;
    } else {
      int bb = m0 >> 12, t0 = m0 & (T_ - 1);
      aSrc[s] = A + ((size_t)bb * H_ * T_ + t0 + r) * D_ + cs;  // head 0 base
    }
  }
#pragma unroll
  for (int s = 0; s < 2; ++s) {
    int u = s * 512 + tid, r = u >> 3, ch = u & 7;
    int cs = (ch ^ (r & 7)) << 3;
    bSrc[s] = Bw + (size_t)(n0 + r) * C_ + cs;
  }
  constexpr size_t ASTEP = (MODE == 0) ? (size_t)BK : (size_t)T_ * D_;

  // Prologue: kt0 -> slot0, kt1 -> slot1; wait kt0 only (vmcnt 6: kt1 in flight).
#pragma unroll
  for (int s = 0; s < 4; ++s) GLD(aSrc[s], (s * 512 + tid) * 8);
#pragma unroll
  for (int s = 0; s < 2; ++s) GLD(bSrc[s], ASL + (s * 512 + tid) * 8);
#pragma unroll
  for (int s = 0; s < 4; ++s) GLD(aSrc[s] + ASTEP, SLOT + (s * 512 + tid) * 8);
#pragma unroll
  for (int s = 0; s < 2; ++s) GLD(bSrc[s] + BK, SLOT + ASL + (s * 512 + tid) * 8);
  asm volatile("s_waitcnt vmcnt(6)" ::: "memory");
  __builtin_amdgcn_s_barrier();

  f32x4 acc[4][4] = {};
  const int lr  = lane & 15;                       // fragment row
  const int lq  = lane >> 4;                       // k-group
  const int co0 = ((0 + lq) ^ (lane & 7)) << 3;    // swizzled chunk, kk=0
  const int co1 = ((4 + lq) ^ (lane & 7)) << 3;    // kk=1

  int rsl = 0;                                     // read slot = kt%3
  for (int kt = 0; kt < NKT; ++kt) {
    const bf16_t* arow = &sm[rsl * SLOT + (wm * 64 + lr) * 64];
    const bf16_t* brow = &sm[rsl * SLOT + ASL + (wn * 64 + lr) * 64];
    const int  wof = ((rsl == 0) ? 2 : rsl - 1) * SLOT;   // slot (kt+2)%3
    const bool st  = (kt + 2 < NKT);
    const size_t ka = (size_t)(kt + 2) * ASTEP;
    const size_t kb = (size_t)(kt + 2) * BK;

    bf16x8 af[4][2], bfr[4][2];

    // ---- P0: read af[0..3] + bfr[0,1]; GLD A units 0..3; MFMA m0123 x n01
#pragma unroll
    for (int i = 0; i < 4; ++i) {
      af[i][0] = *(const bf16x8*)(arow + i * 1024 + co0);
      af[i][1] = *(const bf16x8*)(arow + i * 1024 + co1);
    }
#pragma unroll
    for (int j = 0; j < 2; ++j) {
      bfr[j][0] = *(const bf16x8*)(brow + j * 1024 + co0);
      bfr[j][1] = *(const bf16x8*)(brow + j * 1024 + co1);
    }
    if (st) {
      GLD(aSrc[0] + ka, wof + (0 * 512 + tid) * 8);
      GLD(aSrc[1] + ka, wof + (1 * 512 + tid) * 8);
      GLD(aSrc[2] + ka, wof + (2 * 512 + tid) * 8);
      GLD(aSrc[3] + ka, wof + (3 * 512 + tid) * 8);
    }
    __builtin_amdgcn_sched_barrier(0);
    __builtin_amdgcn_s_barrier();
    asm volatile("s_waitcnt lgkmcnt(0)" ::: "memory");
    __builtin_amdgcn_sched_barrier(0);
    __builtin_amdgcn_s_setprio(1);
#pragma unroll
    for (int i = 0; i < 4; ++i)
#pragma unroll
      for (int j = 0; j < 2; ++j)
#pragma unroll
        for (int kk = 0; kk < 2; ++kk)
          acc[i][j] = __builtin_amdgcn_mfma_f32_16x16x32_bf16(
              af[i][kk], bfr[j][kk], acc[i][j], 0, 0, 0);
    __builtin_amdgcn_s_setprio(0);
    __builtin_amdgcn_sched_barrier(0);
    __builtin_amdgcn_s_barrier();

    // ---- P1: read bfr[2,3]; GLD B units 0,1; MFMA m0123 x n23; boundary
#pragma unroll
    for (int j = 2; j < 4; ++j) {
      bfr[j][0] = *(const bf16x8*)(brow + j * 1024 + co0);
      bfr[j][1] = *(const bf16x8*)(brow + j * 1024 + co1);
    }
    if (st) {
      GLD(bSrc[0] + kb, wof + ASL + (0 * 512 + tid) * 8);
      GLD(bSrc[1] + kb, wof + ASL + (1 * 512 + tid) * 8);
    }
    __builtin_amdgcn_sched_barrier(0);
    __builtin_amdgcn_s_barrier();
    asm volatile("s_waitcnt lgkmcnt(0)" ::: "memory");
    __builtin_amdgcn_sched_barrier(0);
    __builtin_amdgcn_s_setprio(1);
#pragma unroll
    for (int i = 0; i < 4; ++i)
#pragma unroll
      for (int j = 2; j < 4; ++j)
#pragma unroll
        for (int kk = 0; kk < 2; ++kk)
          acc[i][j] = __builtin_amdgcn_mfma_f32_16x16x32_bf16(
              af[i][kk], bfr[j][kk], acc[i][j], 0, 0, 0);
    __builtin_amdgcn_s_setprio(0);
    __builtin_amdgcn_sched_barrier(0);
    if (kt < NKT - 2)       asm volatile("s_waitcnt vmcnt(6)" ::: "memory");
    else if (kt == NKT - 2) asm volatile("s_waitcnt vmcnt(0)" ::: "memory");
    __builtin_amdgcn_s_barrier();
    rsl = (rsl == 2) ? 0 : rsl + 1;
  }

  // Epilogue. C/D layout: col = lane&15, row = (lane>>4)*4 + reg  [m89]
  const int cn = lane & 15;
  const int rq = (lane >> 4) << 2;
  if constexpr (MODE == 0) {
    const int z  = n0 >> 9;                        // BN=128 | 512 -> z uniform
    const float* bias = (z == 0) ? b0 : (z == 1) ? b1 : b2;
    const int bb = m0 >> 12;
    const int t0 = m0 & (T_ - 1);
    bf16_t* plane = (bf16_t*)Outp + (size_t)z * PLANE;
#pragma unroll
    for (int j = 0; j < 4; ++j) {
      const int cc  = (n0 & (C_ - 1)) + wn * 64 + j * 16 + cn;
      const int hh  = cc >> 6, dd = cc & 63;
      const float bvv = bias[cc];
      bf16_t* hb = plane + ((size_t)(bb * H_ + hh) * T_) * D_ + dd;
#pragma unroll
      for (int i = 0; i < 4; ++i)
#pragma unroll
        for (int r = 0; r < 4; ++r) {
          const int t = t0 + wm * 64 + i * 16 + rq + r;
          hb[(size_t)t * D_] = (bf16_t)(acc[i][j][r] + bvv);
        }
    }
  } else {
    float* outp = (float*)Outp;
#pragma unroll
    for (int j = 0; j < 4; ++j) {
      const int n = n0 + wn * 64 + j * 16 + cn;
      const float bvv = b0[n];
#pragma unroll
      for (int i = 0; i < 4; ++i)
#pragma unroll
        for (int r = 0; r < 4; ++r) {
          const int m = m0 + wm * 64 + i * 16 + rq + r;
          outp[(size_t)m * C_ + n] = acc[i][j][r] + bvv;
        }
    }
  }
}

// ---------------------------------------------------------------------------
// Neighborhood attention: 8 threads per (b,h,t), d-octet each; width-8
// shfl_xor score reduce; per-head plane I/O (fully coalesced). Unchanged.
// ---------------------------------------------------------------------------
__global__ __launch_bounds__(256)
void attn_kernel(const bf16_t* __restrict__ qkv, bf16_t* __restrict__ y) {
  const int tid  = threadIdx.x;
  const int sub  = tid & 7;
  const int tl   = tid >> 3;
  const int t    = blockIdx.x * 32 + tl;
  const int h    = blockIdx.y;
  const int b    = blockIdx.z;

  const size_t pl = (size_t)(b * H_ + h) * T_ * D_;
  const bf16_t* q = qkv + pl;
  const bf16_t* k = qkv + (size_t)PLANE + pl;
  const bf16_t* v = qkv + (size_t)2 * PLANE + pl;
  const int c = sub * 8;

  int tj[KS_];
#pragma unroll
  for (int j = 0; j < KS_; ++j) {
    int tt = t - PAD_ + j;
    tj[j] = tt < 0 ? 0 : (tt >= T_ ? T_ - 1 : tt);
  }

  bf16x8 q8 = *(const bf16x8*)(q + (size_t)t * D_ + c);
  float qf[8];
#pragma unroll
  for (int e = 0; e < 8; ++e) qf[e] = (float)q8[e];

  float s[KS_];
#pragma unroll
  for (int j = 0; j < KS_; ++j) {
    bf16x8 k8 = *(const bf16x8*)(k + (size_t)tj[j] * D_ + c);
    float d0 = 0.f;
#pragma unroll
    for (int e = 0; e < 8; ++e) d0 += qf[e] * (float)k8[e];
    s[j] = d0;
  }

#pragma unroll
  for (int m = 1; m < 8; m <<= 1)
#pragma unroll
    for (int j = 0; j < KS_; ++j) s[j] += __shfl_xor(s[j], m, 8);

  float mx = s[0];
#pragma unroll
  for (int j = 1; j < KS_; ++j) mx = fmaxf(mx, s[j]);
  float w[KS_], sum = 0.f;
#pragma unroll
  for (int j = 0; j < KS_; ++j) {
    w[j] = __expf((s[j] - mx) * 0.125f);   // scale = 1/sqrt(64)
    sum += w[j];
  }
  const float inv = 1.f / sum;
#pragma unroll
  for (int j = 0; j < KS_; ++j) w[j] *= inv;

  float o[8] = {0.f, 0.f, 0.f, 0.f, 0.f, 0.f, 0.f, 0.f};
#pragma unroll
  for (int j = 0; j < KS_; ++j) {
    bf16x8 v8 = *(const bf16x8*)(v + (size_t)tj[j] * D_ + c);
#pragma unroll
    for (int e = 0; e < 8; ++e) o[e] += w[j] * (float)v8[e];
  }
  bf16x8 o8;
#pragma unroll
  for (int e = 0; e < 8; ++e) o8[e] = (bf16_t)o[e];
  *(bf16x8*)(y + pl + (size_t)t * D_ + c) = o8;
}

// ---------------------------------------------------------------------------
extern "C" void kernel_launch(void* const* d_in, const int* in_sizes, int n_in,
                              void* d_out, int out_size, void* d_ws, size_t ws_size,
                              hipStream_t stream) {
  const float* x  = (const float*)d_in[0];
  const float* Wq = (const float*)d_in[1];
  const float* bq = (const float*)d_in[2];
  const float* Wk = (const float*)d_in[3];
  const float* bk = (const float*)d_in[4];
  const float* Wv = (const float*)d_in[5];
  const float* bv = (const float*)d_in[6];
  const float* Wo = (const float*)d_in[7];
  const float* bo = (const float*)d_in[8];
  float* out = (float*)d_out;

  // Workspace: Wb 2MB | xb 16.8MB | qkv 50.3MB  (y aliases xb: xb is dead
  // once gemm8p<0> completes; attn writes y, gemm8p<1> reads it). ~69MB.
  bf16_t* Wb  = (bf16_t*)d_ws;
  bf16_t* xb  = Wb + (size_t)4 * C_ * C_;
  bf16_t* qkv = xb + (size_t)PLANE;
  bf16_t* y   = xb;

  conv_all<<<(4 * WU + PLANE / 8) / 256, 256, 0, stream>>>(Wq, Wk, Wv, Wo, x, Wb, xb);
  gemm8p<0><<<dim3(3 * C_ / BN, MTOT / BM), 512, 0, stream>>>(
      xb, Wb, bq, bk, bv, qkv);
  attn_kernel<<<dim3(T_ / 32, H_, B_), 256, 0, stream>>>(qkv, y);
  gemm8p<1><<<dim3(C_ / BN, MTOT / BM), 512, 0, stream>>>(
      y, Wb + (size_t)3 * C_ * C_, bo, nullptr, nullptr, out);
}